// Round 2
// baseline (721.537 us; speedup 1.0000x reference)
//
#include <hip/hip_runtime.h>
#include <hip/hip_bf16.h>
#include <stdint.h>

// Problem constants: x (16,256,64,64) fp32, 32 norm groups, 8 heads, head dim 32.
// All inputs/outputs fp32 (per reference); intermediates bf16 in d_ws.
#define BATCH 16
#define CCH   256
#define NSP   4096   // 64*64
#define QKV_M 768

typedef unsigned short u16;

__device__ __forceinline__ float bf2f(u16 h) {
  union { unsigned int u; float f; } x; x.u = ((unsigned int)h) << 16; return x.f;
}
__device__ __forceinline__ u16 f2bf(float f) {
  union { float f; unsigned int u; } x; x.f = f;
  unsigned int r = 0x7fffu + ((x.u >> 16) & 1u);
  return (u16)((x.u + r) >> 16);
}

// ---------------------------------------------------------------- GroupNorm
// One block per (batch, group): 8 channels * 4096 = 32768 contiguous fp32 elems.
// Reads fp32 x, writes bf16 xn.
__global__ __launch_bounds__(256) void gn_kernel(const float* __restrict__ x,
                                                 const float* __restrict__ gw,
                                                 const float* __restrict__ gb,
                                                 u16* __restrict__ xn) {
  const int blk = blockIdx.x;                 // b*32 + g
  const float* xp = x + (size_t)blk * 32768;
  u16* op = xn + (size_t)blk * 32768;
  const int tid = threadIdx.x;
  const float4* xv = (const float4*)xp;       // 8192 vectors of 4 fp32

  float s = 0.f, ss = 0.f;
  for (int i = tid; i < 8192; i += 256) {
    float4 u = xv[i];
    s  += u.x + u.y + u.z + u.w;
    ss += u.x * u.x + u.y * u.y + u.z * u.z + u.w * u.w;
  }
#pragma unroll
  for (int off = 32; off > 0; off >>= 1) {
    s  += __shfl_down(s, off);
    ss += __shfl_down(ss, off);
  }
  __shared__ float red[8];
  const int wave = tid >> 6, lane = tid & 63;
  if (lane == 0) { red[wave * 2] = s; red[wave * 2 + 1] = ss; }
  __syncthreads();
  const float S  = red[0] + red[2] + red[4] + red[6];
  const float SS = red[1] + red[3] + red[5] + red[7];
  const float mean = S * (1.f / 32768.f);
  const float var  = SS * (1.f / 32768.f) - mean * mean;
  const float rstd = rsqrtf(var + 1e-5f);
  const int gbase = (blk & 31) * 8;

  for (int i = tid; i < 8192; i += 256) {
    float4 u = xv[i];
    const int cl = i >> 10;                   // 1024 float4 per channel
    const float wv = gw[gbase + cl] * rstd;
    const float bv = gb[gbase + cl] - mean * wv;
    ushort4 o;
    o.x = f2bf(u.x * wv + bv);
    o.y = f2bf(u.y * wv + bv);
    o.z = f2bf(u.z * wv + bv);
    o.w = f2bf(u.w * wv + bv);
    *(ushort4*)(op + i * 4) = o;
  }
}

// ---------------------------------------------------------------- GEMM
// C[b][m][n] = sum_c A[m][c] * B[b][c][n] (+ bias[m]); A fp32, B bf16, fp32 acc.
// OUTF32=1 -> fp32 C, else bf16 C. 64x64 tile, BK=16, 256 threads, each 4x4.
template <int OUTF32>
__global__ __launch_bounds__(256) void gemm_mixed(const float* __restrict__ A,
                                                  const u16* __restrict__ Bm,
                                                  const float* __restrict__ bias,
                                                  void* __restrict__ Cm,
                                                  int M, int N, int K) {
  __shared__ __align__(16) float As[16][68];  // [k][m], pad 68 (row = 272B, 16B mult)
  __shared__ __align__(16) float Bs[16][64];  // [k][n]
  const int bz = blockIdx.z;
  const u16* Bb = Bm + (size_t)bz * (size_t)K * N;
  const int m0 = blockIdx.y * 64, n0 = blockIdx.x * 64;
  const int tid = threadIdx.x;
  const int tm = tid >> 4, tn = tid & 15;
  const int arow = tid >> 2;              // 0..63
  const int acol = (tid & 3) * 4;         // 0,4,8,12
  const int brow = tid >> 4;              // 0..15
  const int bcol = (tid & 15) * 4;        // 0..60
  float acc[4][4] = {};

  for (int k0 = 0; k0 < K; k0 += 16) {
    float4  ua = *(const float4*)(A  + (size_t)(m0 + arow) * K + k0 + acol);
    ushort4 ub = *(const ushort4*)(Bb + (size_t)(k0 + brow) * N + n0 + bcol);
    As[acol + 0][arow] = ua.x;
    As[acol + 1][arow] = ua.y;
    As[acol + 2][arow] = ua.z;
    As[acol + 3][arow] = ua.w;
    Bs[brow][bcol + 0] = bf2f(ub.x);
    Bs[brow][bcol + 1] = bf2f(ub.y);
    Bs[brow][bcol + 2] = bf2f(ub.z);
    Bs[brow][bcol + 3] = bf2f(ub.w);
    __syncthreads();
#pragma unroll
    for (int kk = 0; kk < 16; ++kk) {
      const float4 av = *(const float4*)&As[kk][tm * 4];
      const float4 bv = *(const float4*)&Bs[kk][tn * 4];
      const float a[4] = {av.x, av.y, av.z, av.w};
      const float b[4] = {bv.x, bv.y, bv.z, bv.w};
#pragma unroll
      for (int i = 0; i < 4; ++i)
#pragma unroll
        for (int j = 0; j < 4; ++j) acc[i][j] += a[i] * b[j];
    }
    __syncthreads();
  }
#pragma unroll
  for (int i = 0; i < 4; ++i) {
    const int m = m0 + tm * 4 + i;
    const float bv = bias ? bias[m] : 0.f;
    if (OUTF32) {
      float* Cb = (float*)Cm + (size_t)bz * (size_t)M * N;
      float4 o;
      o.x = acc[i][0] + bv; o.y = acc[i][1] + bv;
      o.z = acc[i][2] + bv; o.w = acc[i][3] + bv;
      *(float4*)(Cb + (size_t)m * N + n0 + tn * 4) = o;
    } else {
      u16* Cb = (u16*)Cm + (size_t)bz * (size_t)M * N;
      ushort4 o;
      o.x = f2bf(acc[i][0] + bv); o.y = f2bf(acc[i][1] + bv);
      o.z = f2bf(acc[i][2] + bv); o.w = f2bf(acc[i][3] + bv);
      *(ushort4*)(Cb + (size_t)m * N + n0 + tn * 4) = o;
    }
  }
}

// ---------------------------------------------------------------- softmax on k rows
// One block per row (4096 rows of length 4096), in place on qkv[.., 256..511, ..] (bf16).
__global__ __launch_bounds__(256) void softmax_kernel(u16* __restrict__ qkv) {
  const int blk = blockIdx.x;
  const int b = blk >> 8, r = blk & 255;
  u16* p = qkv + ((size_t)b * QKV_M + 256 + r) * NSP;
  uint4* pv = (uint4*)p;                       // 512 vectors of 8 bf16
  const int tid = threadIdx.x;
  uint4 u0 = pv[tid], u1 = pv[tid + 256];
  float v[16];
  {
    const u16* e0 = (const u16*)&u0; const u16* e1 = (const u16*)&u1;
#pragma unroll
    for (int j = 0; j < 8; ++j) { v[j] = bf2f(e0[j]); v[8 + j] = bf2f(e1[j]); }
  }
  float m = -1e30f;
#pragma unroll
  for (int j = 0; j < 16; ++j) m = fmaxf(m, v[j]);
#pragma unroll
  for (int off = 32; off > 0; off >>= 1) m = fmaxf(m, __shfl_down(m, off));
  __shared__ float rm[4], rs[4];
  const int wave = tid >> 6, lane = tid & 63;
  if (lane == 0) rm[wave] = m;
  __syncthreads();
  m = fmaxf(fmaxf(rm[0], rm[1]), fmaxf(rm[2], rm[3]));
  float s = 0.f;
#pragma unroll
  for (int j = 0; j < 16; ++j) { v[j] = __expf(v[j] - m); s += v[j]; }
#pragma unroll
  for (int off = 32; off > 0; off >>= 1) s += __shfl_down(s, off);
  if (lane == 0) rs[wave] = s;
  __syncthreads();
  s = rs[0] + rs[1] + rs[2] + rs[3];
  const float inv = 1.f / s;
  {
    u16* e0 = (u16*)&u0; u16* e1 = (u16*)&u1;
#pragma unroll
    for (int j = 0; j < 8; ++j) { e0[j] = f2bf(v[j] * inv); e1[j] = f2bf(v[8 + j] * inv); }
  }
  pv[tid] = u0; pv[tid + 256] = u1;
}

// ---------------------------------------------------------------- att = k_sm @ v^T
// One block per (b,h). att[d][e] = sum_n k[d,n]*v[e,n]. LDS chunks of 128 n.
__global__ __launch_bounds__(256) void att_kernel(const u16* __restrict__ qkv,
                                                  float* __restrict__ att) {
  const int bh = blockIdx.x;                   // 0..127
  const int b = bh >> 3, h = bh & 7;
  const u16* kp = qkv + ((size_t)b * QKV_M + 256 + h * 32) * NSP;
  const u16* vp = qkv + ((size_t)b * QKV_M + 512 + h * 32) * NSP;
  __shared__ __align__(16) float ks[32][132];  // row = 528B (16B mult), bank-stagger 4
  __shared__ __align__(16) float vs[32][132];
  const int tid = threadIdx.x;
  const int d0 = (tid >> 4) * 2, e0 = (tid & 15) * 2;
  float a00 = 0.f, a01 = 0.f, a10 = 0.f, a11 = 0.f;

  for (int c0 = 0; c0 < NSP; c0 += 128) {
#pragma unroll
    for (int j = 0; j < 2; ++j) {
      const int idx = tid + j * 256;           // 0..511
      const int row = idx >> 4;                // 16 uint4 per row
      const int col = (idx & 15) * 8;
      uint4 uk = *(const uint4*)(kp + (size_t)row * NSP + c0 + col);
      uint4 uv = *(const uint4*)(vp + (size_t)row * NSP + c0 + col);
      const u16* ek = (const u16*)&uk; const u16* ev = (const u16*)&uv;
#pragma unroll
      for (int t = 0; t < 8; ++t) { ks[row][col + t] = bf2f(ek[t]); vs[row][col + t] = bf2f(ev[t]); }
    }
    __syncthreads();
#pragma unroll
    for (int i = 0; i < 128; i += 4) {
      const float4 k0v = *(const float4*)&ks[d0][i];
      const float4 k1v = *(const float4*)&ks[d0 + 1][i];
      const float4 v0v = *(const float4*)&vs[e0][i];
      const float4 v1v = *(const float4*)&vs[e0 + 1][i];
      a00 += k0v.x * v0v.x + k0v.y * v0v.y + k0v.z * v0v.z + k0v.w * v0v.w;
      a01 += k0v.x * v1v.x + k0v.y * v1v.y + k0v.z * v1v.z + k0v.w * v1v.w;
      a10 += k1v.x * v0v.x + k1v.y * v0v.y + k1v.z * v0v.z + k1v.w * v0v.w;
      a11 += k1v.x * v1v.x + k1v.y * v1v.y + k1v.z * v1v.z + k1v.w * v1v.w;
    }
    __syncthreads();
  }
  float* ap = att + (size_t)bh * 1024;
  ap[(d0 + 0) * 32 + e0 + 0] = a00;
  ap[(d0 + 0) * 32 + e0 + 1] = a01;
  ap[(d0 + 1) * 32 + e0 + 0] = a10;
  ap[(d0 + 1) * 32 + e0 + 1] = a11;
}

// ---------------------------------------------------------------- out = att^T @ q
// grid (16 n-chunks, 8 heads, 16 batches); thread = one n column. bf16 out into ws.
__global__ __launch_bounds__(256) void attout_kernel(const u16* __restrict__ qkv,
                                                     const float* __restrict__ att,
                                                     u16* __restrict__ outb) {
  const int b = blockIdx.z, h = blockIdx.y;
  const int n = blockIdx.x * 256 + threadIdx.x;
  const u16* q = qkv + ((size_t)b * QKV_M + h * 32) * NSP;
  const float* ap = att + ((size_t)b * 8 + h) * 1024;
  __shared__ float as[32][33];
  for (int i = threadIdx.x; i < 1024; i += 256) as[i >> 5][i & 31] = ap[i];
  __syncthreads();
  float qv[32];
#pragma unroll
  for (int d = 0; d < 32; ++d) qv[d] = bf2f(q[(size_t)d * NSP + n]);
#pragma unroll
  for (int e = 0; e < 32; ++e) {
    float acc = 0.f;
#pragma unroll
    for (int d = 0; d < 32; ++d) acc += as[d][e] * qv[d];
    outb[((size_t)b * CCH + h * 32 + e) * NSP + n] = f2bf(acc);
  }
}

// ---------------------------------------------------------------- launch
extern "C" void kernel_launch(void* const* d_in, const int* in_sizes, int n_in,
                              void* d_out, int out_size, void* d_ws, size_t ws_size,
                              hipStream_t stream) {
  const float* x      = (const float*)d_in[0];
  const float* gn_w   = (const float*)d_in[1];
  const float* gn_b   = (const float*)d_in[2];
  const float* w_qkv  = (const float*)d_in[3];
  const float* w_proj = (const float*)d_in[4];
  const float* b_proj = (const float*)d_in[5];
  float* out = (float*)d_out;

  char* ws = (char*)d_ws;
  u16* xn   = (u16*)ws;                                     // 16*256*4096*2 = 32 MiB
  u16* qkv  = (u16*)(ws + (size_t)33554432);                // 16*768*4096*2 = 96 MiB
  float* att = (float*)(ws + (size_t)33554432 + 100663296); // 16*8*1024*4 = 0.5 MiB
  // attout reuses the xn buffer (xn dead after qkv GEMM).

  gn_kernel<<<512, 256, 0, stream>>>(x, gn_w, gn_b, xn);
  gemm_mixed<0><<<dim3(NSP / 64, QKV_M / 64, BATCH), 256, 0, stream>>>(
      w_qkv, xn, nullptr, qkv, QKV_M, NSP, CCH);
  softmax_kernel<<<BATCH * 256, 256, 0, stream>>>(qkv);
  att_kernel<<<BATCH * 8, 256, 0, stream>>>(qkv, att);
  attout_kernel<<<dim3(NSP / 256, 8, BATCH), 256, 0, stream>>>(qkv, att, xn);
  gemm_mixed<1><<<dim3(NSP / 64, CCH / 64, BATCH), 256, 0, stream>>>(
      w_proj, xn, b_proj, out, CCH, NSP, CCH);
}

// Round 3
// 376.996 us; speedup vs baseline: 1.9139x; 1.9139x over previous
//
#include <hip/hip_runtime.h>
#include <stdint.h>

// x (16,256,64,64) fp32; 32 groups; 8 heads; head dim 32. All I/O fp32.
// Intermediates bf16 in d_ws. GEMMs on bf16 MFMA (16x16x32), m97 structure.
#define BATCH 16
#define CCH   256
#define NSP   4096
#define QKV_M 768

typedef unsigned short u16;
typedef short  short8 __attribute__((ext_vector_type(8)));   // 8 bf16 (4 VGPRs)
typedef float  f32x4  __attribute__((ext_vector_type(4)));

__device__ __forceinline__ float bf2f(u16 h) {
  union { unsigned int u; float f; } x; x.u = ((unsigned int)h) << 16; return x.f;
}
__device__ __forceinline__ u16 f2bf(float f) {
  union { float f; unsigned int u; } x; x.f = f;
  unsigned int r = 0x7fffu + ((x.u >> 16) & 1u);
  return (u16)((x.u + r) >> 16);
}

#define GLB(p) ((__attribute__((address_space(1))) void*)(p))
#define LDSP(p) ((__attribute__((address_space(3))) void*)(p))

// ------------------------------------------------ weights fp32 -> bf16
// 196608 (w_qkv) + 65536 (w_proj) elems, 4 per thread, 256x256.
__global__ __launch_bounds__(256) void convw_kernel(const float* __restrict__ wq,
                                                    const float* __restrict__ wp,
                                                    u16* __restrict__ dst) {
  const int i = (blockIdx.x * 256 + threadIdx.x) * 4;
  float4 v = (i < 196608) ? *(const float4*)(wq + i)
                          : *(const float4*)(wp + (i - 196608));
  ushort4 o;
  o.x = f2bf(v.x); o.y = f2bf(v.y); o.z = f2bf(v.z); o.w = f2bf(v.w);
  *(ushort4*)(dst + i) = o;
}

// ------------------------------------------------ GroupNorm stats
// One block per (b,g): 8 ch * 4096 = 32768 contiguous fp32. stats = {mean, rstd}.
__global__ __launch_bounds__(256) void gn_stats(const float* __restrict__ x,
                                                float2* __restrict__ stats) {
  const int blk = blockIdx.x;
  const float4* xv = (const float4*)(x + (size_t)blk * 32768);
  const int tid = threadIdx.x;
  float s = 0.f, ss = 0.f;
  for (int i = tid; i < 8192; i += 256) {
    float4 u = xv[i];
    s  += u.x + u.y + u.z + u.w;
    ss += u.x * u.x + u.y * u.y + u.z * u.z + u.w * u.w;
  }
#pragma unroll
  for (int off = 32; off > 0; off >>= 1) {
    s  += __shfl_down(s, off);
    ss += __shfl_down(ss, off);
  }
  __shared__ float red[8];
  const int wave = tid >> 6, lane = tid & 63;
  if (lane == 0) { red[wave * 2] = s; red[wave * 2 + 1] = ss; }
  __syncthreads();
  if (tid == 0) {
    const float S  = red[0] + red[2] + red[4] + red[6];
    const float SS = red[1] + red[3] + red[5] + red[7];
    const float mean = S * (1.f / 32768.f);
    const float var  = SS * (1.f / 32768.f) - mean * mean;
    stats[blk] = make_float2(mean, rsqrtf(var + 1e-5f));
  }
}

// ------------------------------------------------ GN apply + transpose
// Tile 64c x 64n; read x[b][c][n] coalesced, write xnT[b][n][c] coalesced.
__global__ __launch_bounds__(256) void gn_apply_t(const float* __restrict__ x,
                                                  const float* __restrict__ gw,
                                                  const float* __restrict__ gb,
                                                  const float2* __restrict__ stats,
                                                  u16* __restrict__ xnT) {
  __shared__ u16 ls[64][72];                    // [c][n], pad 72
  const int b = blockIdx.z, c0 = blockIdx.y * 64, n0 = blockIdx.x * 64;
  const int tid = threadIdx.x;
#pragma unroll
  for (int r = 0; r < 4; ++r) {
    const int cc = (tid >> 4) + r * 16;
    const int nn = (tid & 15) * 4;
    const int c = c0 + cc;
    const float2 st = stats[b * 32 + (c >> 3)];
    const float wv = gw[c] * st.y;
    const float bv = gb[c] - st.x * wv;
    float4 u = *(const float4*)(x + ((size_t)b * CCH + c) * NSP + n0 + nn);
    ushort4 o;
    o.x = f2bf(u.x * wv + bv);
    o.y = f2bf(u.y * wv + bv);
    o.z = f2bf(u.z * wv + bv);
    o.w = f2bf(u.w * wv + bv);
    *(ushort4*)&ls[cc][nn] = o;
  }
  __syncthreads();
#pragma unroll
  for (int p = 0; p < 2; ++p) {
    const int idx = tid + p * 256;              // 0..511
    const int nn = idx >> 3;
    const int cb = (idx & 7) * 8;
    u16 tmp[8];
#pragma unroll
    for (int j = 0; j < 8; ++j) tmp[j] = ls[cb + j][nn];
    *(uint4*)(xnT + ((size_t)b * NSP + n0 + nn) * CCH + c0 + cb) = *(uint4*)tmp;
  }
}

// ------------------------------------------------ MFMA GEMM
// C[b][m][n] = sum_c A[m][c]*Bt[b][n][c]; A bf16 MxK(K=256), Bt bf16 NxK.
// 128x128 block, BK=32, 4 waves (2x2), wave = 4x4 tiles of 16x16x32 MFMA.
// Fragment-major LDS staged via global_load_lds width 16.
template <int OUTF32>
__global__ __launch_bounds__(256) void gemm_mfma(const u16* __restrict__ A,
                                                 const u16* __restrict__ Bt,
                                                 const float* __restrict__ bias,
                                                 void* __restrict__ Cm, int M) {
  __shared__ __align__(16) u16 smem[8192];      // A: [0,4096) u16, B: [4096,8192)
  const int tid = threadIdx.x, wave = tid >> 6, lane = tid & 63;
  const int n0 = blockIdx.x * 128, m0 = blockIdx.y * 128, bz = blockIdx.z;
  const u16* Bb = Bt + (size_t)bz * NSP * CCH;

  // staging granules: g in [0,512); granule g covers tile-row (g>>6)*16+(g&15),
  // k-chunk ((g>>4)&3)*8 (8 bf16 = 16B). LDS offset g*16 == fragment-major layout.
  const int g0 = wave * 128 + lane, g1 = g0 + 64;
#define GOFF(g) ((size_t)((((g) >> 6) << 4) + ((g) & 15)) * CCH + (size_t)((((g) >> 4) & 3) * 8))
  const u16* pA0 = A  + (size_t)m0 * CCH + GOFF(g0);
  const u16* pA1 = A  + (size_t)m0 * CCH + GOFF(g1);
  const u16* pB0 = Bb + (size_t)n0 * CCH + GOFF(g0);
  const u16* pB1 = Bb + (size_t)n0 * CCH + GOFF(g1);
  char* lA0 = (char*)smem + wave * 2048;
  char* lA1 = lA0 + 1024;
  char* lB0 = (char*)smem + 8192 + wave * 2048;
  char* lB1 = lB0 + 1024;

  const int wm = wave >> 1, wn = wave & 1;
  f32x4 acc[4][4];
#pragma unroll
  for (int i = 0; i < 4; ++i)
#pragma unroll
    for (int j = 0; j < 4; ++j) acc[i][j] = (f32x4){0.f, 0.f, 0.f, 0.f};

  for (int it = 0; it < 8; ++it) {              // K = 256, BK = 32
    __builtin_amdgcn_global_load_lds(GLB(pA0), LDSP(lA0), 16, 0, 0);
    __builtin_amdgcn_global_load_lds(GLB(pA1), LDSP(lA1), 16, 0, 0);
    __builtin_amdgcn_global_load_lds(GLB(pB0), LDSP(lB0), 16, 0, 0);
    __builtin_amdgcn_global_load_lds(GLB(pB1), LDSP(lB1), 16, 0, 0);
    pA0 += 32; pA1 += 32; pB0 += 32; pB1 += 32;
    __syncthreads();
    short8 af[4], bfr[4];
#pragma unroll
    for (int mt = 0; mt < 4; ++mt)
      af[mt] = *(const short8*)&smem[((wm * 4 + mt) * 64 + lane) * 8];
#pragma unroll
    for (int nt = 0; nt < 4; ++nt)
      bfr[nt] = *(const short8*)&smem[4096 + ((wn * 4 + nt) * 64 + lane) * 8];
#pragma unroll
    for (int mt = 0; mt < 4; ++mt)
#pragma unroll
      for (int nt = 0; nt < 4; ++nt)
        acc[mt][nt] = __builtin_amdgcn_mfma_f32_16x16x32_bf16(af[mt], bfr[nt], acc[mt][nt], 0, 0, 0);
    __syncthreads();
  }

  // C/D: col=lane&15, row=(lane>>4)*4+reg [m89]
  const int colb = n0 + wn * 64 + (lane & 15);
  const int rowb = m0 + wm * 64 + (lane >> 4) * 4;
  if (OUTF32) {
    float* C = (float*)Cm + (size_t)bz * M * NSP;
#pragma unroll
    for (int mt = 0; mt < 4; ++mt) {
#pragma unroll
      for (int r = 0; r < 4; ++r) {
        const int row = rowb + mt * 16 + r;
        const float bv = bias[row];
#pragma unroll
        for (int nt = 0; nt < 4; ++nt)
          C[(size_t)row * NSP + colb + nt * 16] = acc[mt][nt][r] + bv;
      }
    }
  } else {
    u16* C = (u16*)Cm + (size_t)bz * M * NSP;
#pragma unroll
    for (int mt = 0; mt < 4; ++mt)
#pragma unroll
      for (int r = 0; r < 4; ++r) {
        const int row = rowb + mt * 16 + r;
#pragma unroll
        for (int nt = 0; nt < 4; ++nt)
          C[(size_t)row * NSP + colb + nt * 16] = f2bf(acc[mt][nt][r]);
      }
  }
}

// ------------------------------------------------ softmax on k rows (in place)
__global__ __launch_bounds__(256) void softmax_kernel(u16* __restrict__ qkv) {
  const int blk = blockIdx.x;
  const int b = blk >> 8, r = blk & 255;
  u16* p = qkv + ((size_t)b * QKV_M + 256 + r) * NSP;
  uint4* pv = (uint4*)p;
  const int tid = threadIdx.x;
  uint4 u0 = pv[tid], u1 = pv[tid + 256];
  float v[16];
  {
    const u16* e0 = (const u16*)&u0; const u16* e1 = (const u16*)&u1;
#pragma unroll
    for (int j = 0; j < 8; ++j) { v[j] = bf2f(e0[j]); v[8 + j] = bf2f(e1[j]); }
  }
  float m = -1e30f;
#pragma unroll
  for (int j = 0; j < 16; ++j) m = fmaxf(m, v[j]);
#pragma unroll
  for (int off = 32; off > 0; off >>= 1) m = fmaxf(m, __shfl_down(m, off));
  __shared__ float rm[4], rs[4];
  const int wave = tid >> 6, lane = tid & 63;
  if (lane == 0) rm[wave] = m;
  __syncthreads();
  m = fmaxf(fmaxf(rm[0], rm[1]), fmaxf(rm[2], rm[3]));
  float s = 0.f;
#pragma unroll
  for (int j = 0; j < 16; ++j) { v[j] = __expf(v[j] - m); s += v[j]; }
#pragma unroll
  for (int off = 32; off > 0; off >>= 1) s += __shfl_down(s, off);
  if (lane == 0) rs[wave] = s;
  __syncthreads();
  s = rs[0] + rs[1] + rs[2] + rs[3];
  const float inv = 1.f / s;
  {
    u16* e0 = (u16*)&u0; u16* e1 = (u16*)&u1;
#pragma unroll
    for (int j = 0; j < 8; ++j) { e0[j] = f2bf(v[j] * inv); e1[j] = f2bf(v[8 + j] * inv); }
  }
  pv[tid] = u0; pv[tid + 256] = u1;
}

// ------------------------------------------------ att = k_sm @ v^T (32x32 per b,h)
__global__ __launch_bounds__(256) void att_kernel(const u16* __restrict__ qkv,
                                                  float* __restrict__ att) {
  const int bh = blockIdx.x;
  const int b = bh >> 3, h = bh & 7;
  const u16* kp = qkv + ((size_t)b * QKV_M + 256 + h * 32) * NSP;
  const u16* vp = qkv + ((size_t)b * QKV_M + 512 + h * 32) * NSP;
  __shared__ __align__(16) float ks[32][132];
  __shared__ __align__(16) float vs[32][132];
  const int tid = threadIdx.x;
  const int d0 = (tid >> 4) * 2, e0 = (tid & 15) * 2;
  float a00 = 0.f, a01 = 0.f, a10 = 0.f, a11 = 0.f;

  for (int c0 = 0; c0 < NSP; c0 += 128) {
#pragma unroll
    for (int j = 0; j < 2; ++j) {
      const int idx = tid + j * 256;
      const int row = idx >> 4;
      const int col = (idx & 15) * 8;
      uint4 uk = *(const uint4*)(kp + (size_t)row * NSP + c0 + col);
      uint4 uv = *(const uint4*)(vp + (size_t)row * NSP + c0 + col);
      const u16* ek = (const u16*)&uk; const u16* ev = (const u16*)&uv;
#pragma unroll
      for (int t = 0; t < 8; ++t) { ks[row][col + t] = bf2f(ek[t]); vs[row][col + t] = bf2f(ev[t]); }
    }
    __syncthreads();
#pragma unroll
    for (int i = 0; i < 128; i += 4) {
      const float4 k0v = *(const float4*)&ks[d0][i];
      const float4 k1v = *(const float4*)&ks[d0 + 1][i];
      const float4 v0v = *(const float4*)&vs[e0][i];
      const float4 v1v = *(const float4*)&vs[e0 + 1][i];
      a00 += k0v.x * v0v.x + k0v.y * v0v.y + k0v.z * v0v.z + k0v.w * v0v.w;
      a01 += k0v.x * v1v.x + k0v.y * v1v.y + k0v.z * v1v.z + k0v.w * v1v.w;
      a10 += k1v.x * v0v.x + k1v.y * v0v.y + k1v.z * v0v.z + k1v.w * v0v.w;
      a11 += k1v.x * v1v.x + k1v.y * v1v.y + k1v.z * v1v.z + k1v.w * v1v.w;
    }
    __syncthreads();
  }
  float* ap = att + (size_t)bh * 1024;
  ap[(d0 + 0) * 32 + e0 + 0] = a00;
  ap[(d0 + 0) * 32 + e0 + 1] = a01;
  ap[(d0 + 1) * 32 + e0 + 0] = a10;
  ap[(d0 + 1) * 32 + e0 + 1] = a11;
}

// ------------------------------------------------ out = att^T @ q, write outT[b][n][c]
__global__ __launch_bounds__(256) void attout_kernel(const u16* __restrict__ qkv,
                                                     const float* __restrict__ att,
                                                     u16* __restrict__ outT) {
  const int b = blockIdx.z, h = blockIdx.y;
  const int n = blockIdx.x * 256 + threadIdx.x;
  const u16* q = qkv + ((size_t)b * QKV_M + h * 32) * NSP;
  const float* ap = att + ((size_t)b * 8 + h) * 1024;
  __shared__ float as[32][33];
  for (int i = threadIdx.x; i < 1024; i += 256) as[i >> 5][i & 31] = ap[i];
  __syncthreads();
  float qv[32];
#pragma unroll
  for (int d = 0; d < 32; ++d) qv[d] = bf2f(q[(size_t)d * NSP + n]);
  u16 ob[32];
#pragma unroll
  for (int e = 0; e < 32; ++e) {
    float acc = 0.f;
#pragma unroll
    for (int d = 0; d < 32; ++d) acc += as[d][e] * qv[d];
    ob[e] = f2bf(acc);
  }
  u16* orow = outT + ((size_t)b * NSP + n) * CCH + h * 32;
#pragma unroll
  for (int j = 0; j < 4; ++j) ((uint4*)orow)[j] = ((const uint4*)ob)[j];
}

// ------------------------------------------------ launch
extern "C" void kernel_launch(void* const* d_in, const int* in_sizes, int n_in,
                              void* d_out, int out_size, void* d_ws, size_t ws_size,
                              hipStream_t stream) {
  const float* x      = (const float*)d_in[0];
  const float* gn_w   = (const float*)d_in[1];
  const float* gn_b   = (const float*)d_in[2];
  const float* w_qkv  = (const float*)d_in[3];
  const float* w_proj = (const float*)d_in[4];
  const float* b_proj = (const float*)d_in[5];
  float* out = (float*)d_out;

  char* ws = (char*)d_ws;
  u16*    xnT   = (u16*)ws;                                 // 32 MiB [b][n][c]; reused as outT
  u16*    qkv   = (u16*)(ws + 33554432ull);                 // 96 MiB [b][768][n]
  float*  att   = (float*)(ws + 134217728ull);              // 0.5 MiB
  float2* stats = (float2*)(ws + 134742016ull);             // 4 KiB
  u16*    wbf   = (u16*)(ws + 134746112ull);                // 512 KiB (wq 196608 + wp 65536)
  u16* wq_bf = wbf;
  u16* wp_bf = wbf + 196608;

  convw_kernel<<<256, 256, 0, stream>>>(w_qkv, w_proj, wbf);
  gn_stats<<<512, 256, 0, stream>>>(x, stats);
  gn_apply_t<<<dim3(64, 4, 16), 256, 0, stream>>>(x, gn_w, gn_b, stats, xnT);
  gemm_mfma<0><<<dim3(32, 6, 16), 256, 0, stream>>>(wq_bf, xnT, nullptr, qkv, QKV_M);
  softmax_kernel<<<BATCH * 256, 256, 0, stream>>>(qkv);
  att_kernel<<<BATCH * 8, 256, 0, stream>>>(qkv, att);
  attout_kernel<<<dim3(16, 8, 16), 256, 0, stream>>>(qkv, att, xnT);  // xnT now outT
  gemm_mfma<1><<<dim3(32, 2, 16), 256, 0, stream>>>(wp_bf, xnT, b_proj, out, CCH);
}

// Round 4
// 304.327 us; speedup vs baseline: 2.3709x; 1.2388x over previous
//
#include <hip/hip_runtime.h>
#include <stdint.h>

// x (16,256,64,64) fp32; 32 groups; 8 heads; head dim 32. All I/O fp32.
// Intermediates bf16 in d_ws. GEMMs on bf16 MFMA (16x16x32), m97 structure.
// Softmax folded into att via linearity: att = diag(1/l) * sum_n exp(k-m) v.
#define BATCH 16
#define CCH   256
#define NSP   4096
#define QKV_M 768

typedef unsigned short u16;
typedef short  short8 __attribute__((ext_vector_type(8)));   // 8 bf16 (4 VGPRs)
typedef float  f32x4  __attribute__((ext_vector_type(4)));

__device__ __forceinline__ float bf2f(u16 h) {
  union { unsigned int u; float f; } x; x.u = ((unsigned int)h) << 16; return x.f;
}
__device__ __forceinline__ u16 f2bf(float f) {
  union { float f; unsigned int u; } x; x.f = f;
  unsigned int r = 0x7fffu + ((x.u >> 16) & 1u);
  return (u16)((x.u + r) >> 16);
}

#define GLB(p) ((__attribute__((address_space(1))) void*)(p))
#define LDSP(p) ((__attribute__((address_space(3))) void*)(p))

// ------------------------------------------------ weights fp32 -> bf16
__global__ __launch_bounds__(256) void convw_kernel(const float* __restrict__ wq,
                                                    const float* __restrict__ wp,
                                                    u16* __restrict__ dst) {
  const int i = (blockIdx.x * 256 + threadIdx.x) * 4;
  float4 v = (i < 196608) ? *(const float4*)(wq + i)
                          : *(const float4*)(wp + (i - 196608));
  ushort4 o;
  o.x = f2bf(v.x); o.y = f2bf(v.y); o.z = f2bf(v.z); o.w = f2bf(v.w);
  *(ushort4*)(dst + i) = o;
}

// ------------------------------------------------ GroupNorm stats
__global__ __launch_bounds__(256) void gn_stats(const float* __restrict__ x,
                                                float2* __restrict__ stats) {
  const int blk = blockIdx.x;
  const float4* xv = (const float4*)(x + (size_t)blk * 32768);
  const int tid = threadIdx.x;
  float s = 0.f, ss = 0.f;
  for (int i = tid; i < 8192; i += 256) {
    float4 u = xv[i];
    s  += u.x + u.y + u.z + u.w;
    ss += u.x * u.x + u.y * u.y + u.z * u.z + u.w * u.w;
  }
#pragma unroll
  for (int off = 32; off > 0; off >>= 1) {
    s  += __shfl_down(s, off);
    ss += __shfl_down(ss, off);
  }
  __shared__ float red[8];
  const int wave = tid >> 6, lane = tid & 63;
  if (lane == 0) { red[wave * 2] = s; red[wave * 2 + 1] = ss; }
  __syncthreads();
  if (tid == 0) {
    const float S  = red[0] + red[2] + red[4] + red[6];
    const float SS = red[1] + red[3] + red[5] + red[7];
    const float mean = S * (1.f / 32768.f);
    const float var  = SS * (1.f / 32768.f) - mean * mean;
    stats[blk] = make_float2(mean, rsqrtf(var + 1e-5f));
  }
}

// ------------------------------------------------ GN apply + transpose
__global__ __launch_bounds__(256) void gn_apply_t(const float* __restrict__ x,
                                                  const float* __restrict__ gw,
                                                  const float* __restrict__ gb,
                                                  const float2* __restrict__ stats,
                                                  u16* __restrict__ xnT) {
  __shared__ u16 ls[64][72];                    // [c][n], pad 72
  const int b = blockIdx.z, c0 = blockIdx.y * 64, n0 = blockIdx.x * 64;
  const int tid = threadIdx.x;
#pragma unroll
  for (int r = 0; r < 4; ++r) {
    const int cc = (tid >> 4) + r * 16;
    const int nn = (tid & 15) * 4;
    const int c = c0 + cc;
    const float2 st = stats[b * 32 + (c >> 3)];
    const float wv = gw[c] * st.y;
    const float bv = gb[c] - st.x * wv;
    float4 u = *(const float4*)(x + ((size_t)b * CCH + c) * NSP + n0 + nn);
    ushort4 o;
    o.x = f2bf(u.x * wv + bv);
    o.y = f2bf(u.y * wv + bv);
    o.z = f2bf(u.z * wv + bv);
    o.w = f2bf(u.w * wv + bv);
    *(ushort4*)&ls[cc][nn] = o;
  }
  __syncthreads();
#pragma unroll
  for (int p = 0; p < 2; ++p) {
    const int idx = tid + p * 256;              // 0..511
    const int nn = idx >> 3;
    const int cb = (idx & 7) * 8;
    u16 tmp[8];
#pragma unroll
    for (int j = 0; j < 8; ++j) tmp[j] = ls[cb + j][nn];
    *(uint4*)(xnT + ((size_t)b * NSP + n0 + nn) * CCH + c0 + cb) = *(uint4*)tmp;
  }
}

// ------------------------------------------------ MFMA GEMM (m97 structure)
// C[b][m][n] = sum_c A[m][c]*Bt[b][n][c]; A bf16 MxK(K=256), Bt bf16 NxK.
template <int OUTF32>
__global__ __launch_bounds__(256) void gemm_mfma(const u16* __restrict__ A,
                                                 const u16* __restrict__ Bt,
                                                 const float* __restrict__ bias,
                                                 void* __restrict__ Cm, int M) {
  __shared__ __align__(16) u16 smem[8192];      // A: [0,4096), B: [4096,8192)
  const int tid = threadIdx.x, wave = tid >> 6, lane = tid & 63;
  const int n0 = blockIdx.x * 128, m0 = blockIdx.y * 128, bz = blockIdx.z;
  const u16* Bb = Bt + (size_t)bz * NSP * CCH;

  const int g0 = wave * 128 + lane, g1 = g0 + 64;
#define GOFF(g) ((size_t)((((g) >> 6) << 4) + ((g) & 15)) * CCH + (size_t)((((g) >> 4) & 3) * 8))
  const u16* pA0 = A  + (size_t)m0 * CCH + GOFF(g0);
  const u16* pA1 = A  + (size_t)m0 * CCH + GOFF(g1);
  const u16* pB0 = Bb + (size_t)n0 * CCH + GOFF(g0);
  const u16* pB1 = Bb + (size_t)n0 * CCH + GOFF(g1);
  char* lA0 = (char*)smem + wave * 2048;
  char* lA1 = lA0 + 1024;
  char* lB0 = (char*)smem + 8192 + wave * 2048;
  char* lB1 = lB0 + 1024;

  const int wm = wave >> 1, wn = wave & 1;
  f32x4 acc[4][4];
#pragma unroll
  for (int i = 0; i < 4; ++i)
#pragma unroll
    for (int j = 0; j < 4; ++j) acc[i][j] = (f32x4){0.f, 0.f, 0.f, 0.f};

  for (int it = 0; it < 8; ++it) {              // K = 256, BK = 32
    __builtin_amdgcn_global_load_lds(GLB(pA0), LDSP(lA0), 16, 0, 0);
    __builtin_amdgcn_global_load_lds(GLB(pA1), LDSP(lA1), 16, 0, 0);
    __builtin_amdgcn_global_load_lds(GLB(pB0), LDSP(lB0), 16, 0, 0);
    __builtin_amdgcn_global_load_lds(GLB(pB1), LDSP(lB1), 16, 0, 0);
    pA0 += 32; pA1 += 32; pB0 += 32; pB1 += 32;
    __syncthreads();
    short8 af[4], bfr[4];
#pragma unroll
    for (int mt = 0; mt < 4; ++mt)
      af[mt] = *(const short8*)&smem[((wm * 4 + mt) * 64 + lane) * 8];
#pragma unroll
    for (int nt = 0; nt < 4; ++nt)
      bfr[nt] = *(const short8*)&smem[4096 + ((wn * 4 + nt) * 64 + lane) * 8];
#pragma unroll
    for (int mt = 0; mt < 4; ++mt)
#pragma unroll
      for (int nt = 0; nt < 4; ++nt)
        acc[mt][nt] = __builtin_amdgcn_mfma_f32_16x16x32_bf16(af[mt], bfr[nt], acc[mt][nt], 0, 0, 0);
    __syncthreads();
  }

  const int colb = n0 + wn * 64 + (lane & 15);
  const int rowb = m0 + wm * 64 + (lane >> 4) * 4;
  if (OUTF32) {
    float* C = (float*)Cm + (size_t)bz * M * NSP;
#pragma unroll
    for (int mt = 0; mt < 4; ++mt) {
#pragma unroll
      for (int r = 0; r < 4; ++r) {
        const int row = rowb + mt * 16 + r;
        const float bv = bias[row];
#pragma unroll
        for (int nt = 0; nt < 4; ++nt)
          C[(size_t)row * NSP + colb + nt * 16] = acc[mt][nt][r] + bv;
      }
    }
  } else {
    u16* C = (u16*)Cm + (size_t)bz * M * NSP;
#pragma unroll
    for (int mt = 0; mt < 4; ++mt)
#pragma unroll
      for (int r = 0; r < 4; ++r) {
        const int row = rowb + mt * 16 + r;
#pragma unroll
        for (int nt = 0; nt < 4; ++nt)
          C[(size_t)row * NSP + colb + nt * 16] = f2bf(acc[mt][nt][r]);
      }
  }
}

// ------------------------------------------------ k row stats: m = max, l = sum exp(k-m)
// One block per k-row (4096 rows, 4096 elems each). Blocks 0..127 also zero att.
__global__ __launch_bounds__(256) void kstat_kernel(const u16* __restrict__ qkv,
                                                    float2* __restrict__ kst,
                                                    float* __restrict__ att) {
  const int blk = blockIdx.x;                  // b*256 + hd
  const int tid = threadIdx.x;
  if (blk < 128) {                             // zero the att accumulator (512 KiB)
    float4 z = {0.f, 0.f, 0.f, 0.f};
    *(float4*)(att + blk * 1024 + tid * 4) = z;
  }
  const int b = blk >> 8, hd = blk & 255;
  const u16* p = qkv + ((size_t)b * QKV_M + 256 + hd) * NSP;
  const uint4* pv = (const uint4*)p;
  uint4 u0 = pv[tid], u1 = pv[tid + 256];
  float v[16];
  {
    const u16* e0 = (const u16*)&u0; const u16* e1 = (const u16*)&u1;
#pragma unroll
    for (int j = 0; j < 8; ++j) { v[j] = bf2f(e0[j]); v[8 + j] = bf2f(e1[j]); }
  }
  float m = -1e30f;
#pragma unroll
  for (int j = 0; j < 16; ++j) m = fmaxf(m, v[j]);
#pragma unroll
  for (int off = 32; off > 0; off >>= 1) m = fmaxf(m, __shfl_down(m, off));
  __shared__ float rm[4], rs[4];
  const int wave = tid >> 6, lane = tid & 63;
  if (lane == 0) rm[wave] = m;
  __syncthreads();
  m = fmaxf(fmaxf(rm[0], rm[1]), fmaxf(rm[2], rm[3]));
  float s = 0.f;
#pragma unroll
  for (int j = 0; j < 16; ++j) s += __expf(v[j] - m);
#pragma unroll
  for (int off = 32; off > 0; off >>= 1) s += __shfl_down(s, off);
  if (lane == 0) rs[wave] = s;
  __syncthreads();
  if (tid == 0) kst[blk] = make_float2(m, rs[0] + rs[1] + rs[2] + rs[3]);
}

// ------------------------------------------------ att += partial sum_n exp(k-m) v
// grid (16 n-chunks, 8 h, 16 b); each block: 256 n, atomicAdd into att[bh][32][32].
__global__ __launch_bounds__(256) void att2_kernel(const u16* __restrict__ qkv,
                                                   const float2* __restrict__ kst,
                                                   float* __restrict__ att) {
  const int b = blockIdx.z, h = blockIdx.y;
  const int bh = b * 8 + h;
  const int nbase = blockIdx.x * 256;
  const u16* kp = qkv + ((size_t)b * QKV_M + 256 + h * 32) * NSP;
  const u16* vp = qkv + ((size_t)b * QKV_M + 512 + h * 32) * NSP;
  __shared__ __align__(16) float ks[32][132];
  __shared__ __align__(16) float vs[32][132];
  __shared__ float ms[32];
  const int tid = threadIdx.x;
  if (tid < 32) ms[tid] = kst[bh * 32 + tid].x;
  const int d0 = (tid >> 4) * 2, e0 = (tid & 15) * 2;
  float a00 = 0.f, a01 = 0.f, a10 = 0.f, a11 = 0.f;
  __syncthreads();

  for (int c0 = nbase; c0 < nbase + 256; c0 += 128) {
#pragma unroll
    for (int j = 0; j < 2; ++j) {
      const int idx = tid + j * 256;
      const int row = idx >> 4;
      const int col = (idx & 15) * 8;
      uint4 uk = *(const uint4*)(kp + (size_t)row * NSP + c0 + col);
      uint4 uv = *(const uint4*)(vp + (size_t)row * NSP + c0 + col);
      const u16* ek = (const u16*)&uk; const u16* ev = (const u16*)&uv;
      const float mr = ms[row];
#pragma unroll
      for (int t = 0; t < 8; ++t) {
        ks[row][col + t] = __expf(bf2f(ek[t]) - mr);
        vs[row][col + t] = bf2f(ev[t]);
      }
    }
    __syncthreads();
#pragma unroll
    for (int i = 0; i < 128; i += 4) {
      const float4 k0v = *(const float4*)&ks[d0][i];
      const float4 k1v = *(const float4*)&ks[d0 + 1][i];
      const float4 v0v = *(const float4*)&vs[e0][i];
      const float4 v1v = *(const float4*)&vs[e0 + 1][i];
      a00 += k0v.x * v0v.x + k0v.y * v0v.y + k0v.z * v0v.z + k0v.w * v0v.w;
      a01 += k0v.x * v1v.x + k0v.y * v1v.y + k0v.z * v1v.z + k0v.w * v1v.w;
      a10 += k1v.x * v0v.x + k1v.y * v0v.y + k1v.z * v0v.z + k1v.w * v0v.w;
      a11 += k1v.x * v1v.x + k1v.y * v1v.y + k1v.z * v1v.z + k1v.w * v1v.w;
    }
    __syncthreads();
  }
  float* ap = att + (size_t)bh * 1024;
  atomicAdd(&ap[(d0 + 0) * 32 + e0 + 0], a00);
  atomicAdd(&ap[(d0 + 0) * 32 + e0 + 1], a01);
  atomicAdd(&ap[(d0 + 1) * 32 + e0 + 0], a10);
  atomicAdd(&ap[(d0 + 1) * 32 + e0 + 1], a11);
}

// ------------------------------------------------ out = (att/l)^T @ q -> outT[b][n][c]
__global__ __launch_bounds__(256) void attout_kernel(const u16* __restrict__ qkv,
                                                     const float* __restrict__ att,
                                                     const float2* __restrict__ kst,
                                                     u16* __restrict__ outT) {
  const int b = blockIdx.z, h = blockIdx.y;
  const int bh = b * 8 + h;
  const int n = blockIdx.x * 256 + threadIdx.x;
  const u16* q = qkv + ((size_t)b * QKV_M + h * 32) * NSP;
  const float* ap = att + (size_t)bh * 1024;
  __shared__ float as[32][33];
  for (int i = threadIdx.x; i < 1024; i += 256) {
    const int d = i >> 5;
    as[d][i & 31] = ap[i] / kst[bh * 32 + d].y;   // fold softmax 1/l_d here
  }
  __syncthreads();
  float qv[32];
#pragma unroll
  for (int d = 0; d < 32; ++d) qv[d] = bf2f(q[(size_t)d * NSP + n]);
  u16 ob[32];
#pragma unroll
  for (int e = 0; e < 32; ++e) {
    float acc = 0.f;
#pragma unroll
    for (int d = 0; d < 32; ++d) acc += as[d][e] * qv[d];
    ob[e] = f2bf(acc);
  }
  u16* orow = outT + ((size_t)b * NSP + n) * CCH + h * 32;
#pragma unroll
  for (int j = 0; j < 4; ++j) ((uint4*)orow)[j] = ((const uint4*)ob)[j];
}

// ------------------------------------------------ launch
extern "C" void kernel_launch(void* const* d_in, const int* in_sizes, int n_in,
                              void* d_out, int out_size, void* d_ws, size_t ws_size,
                              hipStream_t stream) {
  const float* x      = (const float*)d_in[0];
  const float* gn_w   = (const float*)d_in[1];
  const float* gn_b   = (const float*)d_in[2];
  const float* w_qkv  = (const float*)d_in[3];
  const float* w_proj = (const float*)d_in[4];
  const float* b_proj = (const float*)d_in[5];
  float* out = (float*)d_out;

  char* ws = (char*)d_ws;
  u16*    xnT   = (u16*)ws;                                 // 32 MiB [b][n][c]; reused as outT
  u16*    qkv   = (u16*)(ws + 33554432ull);                 // 96 MiB [b][768][n]
  float*  att   = (float*)(ws + 134217728ull);              // 512 KiB [bh][32][32]
  float2* stats = (float2*)(ws + 134742016ull);             // 4 KiB
  u16*    wbf   = (u16*)(ws + 134746112ull);                // 512 KiB
  float2* kst   = (float2*)(ws + 135270400ull);             // 32 KiB [bh*32+d] = {m, l}
  u16* wq_bf = wbf;
  u16* wp_bf = wbf + 196608;

  convw_kernel<<<256, 256, 0, stream>>>(w_qkv, w_proj, wbf);
  gn_stats<<<512, 256, 0, stream>>>(x, stats);
  gn_apply_t<<<dim3(64, 4, 16), 256, 0, stream>>>(x, gn_w, gn_b, stats, xnT);
  gemm_mfma<0><<<dim3(32, 6, 16), 256, 0, stream>>>(wq_bf, xnT, nullptr, qkv, QKV_M);
  kstat_kernel<<<4096, 256, 0, stream>>>(qkv, kst, att);
  att2_kernel<<<dim3(16, 8, 16), 256, 0, stream>>>(qkv, kst, att);
  attout_kernel<<<dim3(16, 8, 16), 256, 0, stream>>>(qkv, att, kst, xnT); // xnT now outT
  gemm_mfma<1><<<dim3(32, 2, 16), 256, 0, stream>>>(wp_bf, xnT, b_proj, out, CCH);
}